// Round 9
// baseline (88.573 us; speedup 1.0000x reference)
//
#include <hip/hip_runtime.h>

// Problem constants
#define HSZ 32
#define HP1 33
#define M3 35937            // 33^3 (flattened j,k,l)
#define M3P 35952           // padded to multiple of 16 (2247*16)
#define TI_STRIDE 1149984   // 33^3 * 32 floats (stride of T over i)
#define NBLK 2247           // M3P / 16, one wave per block
#define NT 64               // partial output tiles (atomic contention 2247/64 ~ 35)

// ws layout (bytes):
//   a0T   @ 0        : 33*32 floats (a0 transposed, [i][b])
//   D     @ 8192     : 32*35952 floats = 4,601,856 B (zero-padded tail)
//   tiles @ 4610048  : 64*1024 floats = 262,144 B
//   cnt   @ 4872192  : 1 uint (last-block-done counter)
#define OFF_A0T   0
#define OFF_D     8192
#define OFF_TILES 4610048
#define OFF_CNT   4872192

typedef short bf16x8 __attribute__((ext_vector_type(8)));
typedef float f32x16 __attribute__((ext_vector_type(16)));

__device__ inline short f2bf(float f) {
  unsigned u = __builtin_bit_cast(unsigned, f);
  u += 0x7FFFu + ((u >> 16) & 1u);   // round-to-nearest-even
  return (short)(u >> 16);
}

// Prologue: D[b][m] = a1*a2*a3 (0 in pad), a0T[i][b], zero tiles + counter.
__global__ __launch_bounds__(256) void k_pre(const float* __restrict__ nh,
                                             float* __restrict__ a0T,
                                             float* __restrict__ D,
                                             float* __restrict__ tiles,
                                             unsigned* __restrict__ cnt) {
  const int b = blockIdx.y;
  const int m = blockIdx.x * 256 + threadIdx.x;
  if (m < M3P) {
    float v = 0.f;
    if (m < M3) {
      const int j = m / 1089;
      const int r = m - j * 1089;
      const int k = r / 33;
      const int l = r - k * 33;
      const float a1 = (j < HSZ) ? nh[(b * 4 + 1) * HSZ + j] : 1.0f;
      const float a2 = (k < HSZ) ? nh[(b * 4 + 2) * HSZ + k] : 1.0f;
      const float a3 = (l < HSZ) ? nh[(b * 4 + 3) * HSZ + l] : 1.0f;
      v = a1 * a2 * a3;
    }
    D[(size_t)b * M3P + m] = v;
  }
  if (blockIdx.x == 0 && threadIdx.x < HP1) {
    const int i = threadIdx.x;
    a0T[i * 32 + b] = (i < HSZ) ? nh[(b * 4 + 0) * HSZ + i] : 1.0f;
  }
  if (b == 1 && blockIdx.x < 64) {  // 64 blocks * 256 threads * 16B = 256 KB
    ((float4*)tiles)[blockIdx.x * 256 + threadIdx.x] =
        make_float4(0.f, 0.f, 0.f, 0.f);
  }
  if (b == 2 && blockIdx.x == 0 && threadIdx.x == 0) *cnt = 0u;
}

// Main: one wave per block; block owns m-chunk [m0, m0+16).
// acc[32b x 32o] += sum_i sum_{mm} (a0[b,i]*D[b,mm]) * T[i][mm][o] via
// v_mfma_f32_32x32x16_bf16. T is read exactly once device-wide, coalesced.
// Last block to finish folds the NT partial tiles into d_out (no k_red).
__global__ __launch_bounds__(64) void k_main(const float* __restrict__ T,
                                             const float* __restrict__ a0T,
                                             const float* __restrict__ D,
                                             float* __restrict__ tiles,
                                             unsigned* __restrict__ cnt,
                                             float* __restrict__ out) {
  const int blk = blockIdx.x;
  const int m0 = blk * 16;
  const int l = (int)threadIdx.x;  // 0..63
  const int bo = l & 31;           // A row (b) / B col (o)
  const int g = l >> 5;            // k-group: k = 8*g + e

  // A-side D fragment (fp32, reused across all 33 i): D[bo][m0+8g+e]
  const float* dp = D + (size_t)bo * M3P + m0 + 8 * g;
  float df[8];
  *(float4*)(df)     = *(const float4*)(dp);
  *(float4*)(df + 4) = *(const float4*)(dp + 4);

  // Per-lane T element offsets for the 8 k's (clamped in the zero-padded tail)
  size_t toff[8];
#pragma unroll
  for (int e = 0; e < 8; ++e) {
    int mm = m0 + 8 * g + e;
    if (mm > M3 - 1) mm = M3 - 1;  // A-frag is 0 there (D pad), value ignored
    toff[e] = (size_t)mm * 32 + bo;
  }

  f32x16 acc = {};

  // software pipeline: loads for i+1 in flight during cvt+MFMA of i
  float tv[8];
#pragma unroll
  for (int e = 0; e < 8; ++e) tv[e] = T[toff[e]];
  float a0c = a0T[bo];

  for (int i = 0; i < HP1; ++i) {
    float tn[8];
    float a0n = 0.f;
    if (i < HP1 - 1) {
      const float* Tn = T + (size_t)(i + 1) * TI_STRIDE;
#pragma unroll
      for (int e = 0; e < 8; ++e) tn[e] = Tn[toff[e]];
      a0n = a0T[(i + 1) * 32 + bo];
    }
    bf16x8 af, bfr;
#pragma unroll
    for (int e = 0; e < 8; ++e) {
      af[e]  = f2bf(a0c * df[e]);
      bfr[e] = f2bf(tv[e]);
    }
    acc = __builtin_amdgcn_mfma_f32_32x32x16_bf16(af, bfr, acc, 0, 0, 0);
#pragma unroll
    for (int e = 0; e < 8; ++e) tv[e] = tn[e];
    a0c = a0n;
  }

  // Accumulate into one of NT partial tiles.
  // C/D layout (verified m74/m101): col=lane&31, row=(r&3)+8*(r>>2)+4*(lane>>5)
  float* tp = tiles + (size_t)(blk & (NT - 1)) * 1024;
#pragma unroll
  for (int r = 0; r < 16; ++r) {
    const int brow = (r & 3) + 8 * (r >> 2) + 4 * g;
    atomicAdd(tp + brow * 32 + bo, acc[r]);
  }

  // Last-block-done: fold the NT tiles into out (saves the k_red dispatch).
  __threadfence();  // my tile atomics are device-visible before the count
  unsigned done = 0;
  if (l == 0) done = atomicAdd(cnt, 1u);
  done = __builtin_amdgcn_readfirstlane(done);
  if (done == NBLK - 1) {
    __threadfence();  // acquire: all other blocks' tile atomics visible
    float4 val[4];
#pragma unroll
    for (int q = 0; q < 4; ++q) val[q] = make_float4(0.f, 0.f, 0.f, 0.f);
#pragma unroll 4
    for (int t = 0; t < NT; ++t) {
#pragma unroll
      for (int q = 0; q < 4; ++q) {
        const float4 v =
            *(const float4*)(tiles + (size_t)t * 1024 + q * 256 + l * 4);
        val[q].x += v.x; val[q].y += v.y; val[q].z += v.z; val[q].w += v.w;
      }
    }
#pragma unroll
    for (int q = 0; q < 4; ++q) *(float4*)(out + q * 256 + l * 4) = val[q];
  }
}

extern "C" void kernel_launch(void* const* d_in, const int* in_sizes, int n_in,
                              void* d_out, int out_size, void* d_ws, size_t ws_size,
                              hipStream_t stream) {
  const float* nh = (const float*)d_in[0];  // [32,4,32]
  const float* T  = (const float*)d_in[1];  // [33,33,33,33,32]
  float* out = (float*)d_out;               // [32,32] fp32
  char* ws = (char*)d_ws;
  float* a0T      = (float*)(ws + OFF_A0T);
  float* D        = (float*)(ws + OFF_D);
  float* tiles    = (float*)(ws + OFF_TILES);
  unsigned* cnt   = (unsigned*)(ws + OFF_CNT);

  k_pre<<<dim3(141, 32), 256, 0, stream>>>(nh, a0T, D, tiles, cnt);
  k_main<<<NBLK, 64, 0, stream>>>(T, a0T, D, tiles, cnt, out);
}

// Round 10
// 43.305 us; speedup vs baseline: 2.0453x; 2.0453x over previous
//
#include <hip/hip_runtime.h>

// Problem constants
#define HSZ 32
#define HP1 33
#define M3 35937            // 33^3 (flattened j,k,l)
#define M3P 35952           // padded to multiple of 16 (2247*16)
#define TI_STRIDE 1149984   // 33^3 * 32 floats (stride of T over i)
#define NBLK 2247           // M3P / 16, one wave per block
#define NT 64               // partial output tiles (atomic contention 2247/64 ~ 35)

// ws layout (bytes):
//   a0T   @ 0        : 33*32 floats (a0 transposed, [i][b])
//   D     @ 8192     : 32*35952 floats = 4,601,856 B (zero-padded tail)
//   tiles @ 4610048  : 64*1024 floats = 262,144 B      total ~4.9 MB
#define OFF_A0T   0
#define OFF_D     8192
#define OFF_TILES 4610048

typedef short bf16x8 __attribute__((ext_vector_type(8)));
typedef float f32x16 __attribute__((ext_vector_type(16)));

__device__ inline short f2bf(float f) {
  unsigned u = __builtin_bit_cast(unsigned, f);
  u += 0x7FFFu + ((u >> 16) & 1u);   // round-to-nearest-even
  return (short)(u >> 16);
}

// Prologue: D[b][m] = a1*a2*a3 (0 in pad), a0T[i][b], zero the partial tiles.
__global__ __launch_bounds__(256) void k_pre(const float* __restrict__ nh,
                                             float* __restrict__ a0T,
                                             float* __restrict__ D,
                                             float* __restrict__ tiles) {
  const int b = blockIdx.y;
  const int m = blockIdx.x * 256 + threadIdx.x;
  if (m < M3P) {
    float v = 0.f;
    if (m < M3) {
      const int j = m / 1089;
      const int r = m - j * 1089;
      const int k = r / 33;
      const int l = r - k * 33;
      const float a1 = (j < HSZ) ? nh[(b * 4 + 1) * HSZ + j] : 1.0f;
      const float a2 = (k < HSZ) ? nh[(b * 4 + 2) * HSZ + k] : 1.0f;
      const float a3 = (l < HSZ) ? nh[(b * 4 + 3) * HSZ + l] : 1.0f;
      v = a1 * a2 * a3;
    }
    D[(size_t)b * M3P + m] = v;
  }
  if (blockIdx.x == 0 && threadIdx.x < HP1) {
    const int i = threadIdx.x;
    a0T[i * 32 + b] = (i < HSZ) ? nh[(b * 4 + 0) * HSZ + i] : 1.0f;
  }
  if (b == 1 && blockIdx.x < 64) {  // 64 blocks * 256 threads * 16B = 256 KB
    ((float4*)tiles)[blockIdx.x * 256 + threadIdx.x] =
        make_float4(0.f, 0.f, 0.f, 0.f);
  }
}

// Main: one wave per block; block owns m-chunk [m0, m0+16).
// acc[32b x 32o] += sum_i sum_{mm} (a0[b,i]*D[b,mm]) * T[i][mm][o] via
// v_mfma_f32_32x32x16_bf16. T is read exactly once device-wide, coalesced.
// ONLY change vs round-8 baseline: distance-2 prefetch (tn1/tn2) to double
// in-flight load bytes per wave (Little's-law concurrency).
__global__ __launch_bounds__(64) void k_main(const float* __restrict__ T,
                                             const float* __restrict__ a0T,
                                             const float* __restrict__ D,
                                             float* __restrict__ tiles) {
  const int blk = blockIdx.x;
  const int m0 = blk * 16;
  const int l = (int)threadIdx.x;  // 0..63
  const int bo = l & 31;           // A row (b) / B col (o)
  const int g = l >> 5;            // k-group: k = 8*g + e

  // A-side D fragment (fp32, reused across all 33 i): D[bo][m0+8g+e]
  const float* dp = D + (size_t)bo * M3P + m0 + 8 * g;
  float df[8];
  *(float4*)(df)     = *(const float4*)(dp);
  *(float4*)(df + 4) = *(const float4*)(dp + 4);

  // Per-lane T element offsets for the 8 k's (clamped in the zero-padded tail)
  size_t toff[8];
#pragma unroll
  for (int e = 0; e < 8; ++e) {
    int mm = m0 + 8 * g + e;
    if (mm > M3 - 1) mm = M3 - 1;  // A-frag is 0 there (D pad), value ignored
    toff[e] = (size_t)mm * 32 + bo;
  }

  f32x16 acc = {};

  // distance-2 software pipeline: rows i+1 and i+2 in flight during compute of i
  float tv[8], tn1[8];
#pragma unroll
  for (int e = 0; e < 8; ++e) tv[e] = T[toff[e]];
  float a0c = a0T[bo];
  {
    const float* Tp = T + (size_t)1 * TI_STRIDE;
#pragma unroll
    for (int e = 0; e < 8; ++e) tn1[e] = Tp[toff[e]];
  }
  float a0n1 = a0T[1 * 32 + bo];

  for (int i = 0; i < HP1; ++i) {
    float tn2[8];
    float a0n2 = 0.f;
    if (i < HP1 - 2) {
      const float* Tn = T + (size_t)(i + 2) * TI_STRIDE;
#pragma unroll
      for (int e = 0; e < 8; ++e) tn2[e] = Tn[toff[e]];
      a0n2 = a0T[(i + 2) * 32 + bo];
    }
    bf16x8 af, bfr;
#pragma unroll
    for (int e = 0; e < 8; ++e) {
      af[e]  = f2bf(a0c * df[e]);
      bfr[e] = f2bf(tv[e]);
    }
    acc = __builtin_amdgcn_mfma_f32_32x32x16_bf16(af, bfr, acc, 0, 0, 0);
#pragma unroll
    for (int e = 0; e < 8; ++e) { tv[e] = tn1[e]; tn1[e] = tn2[e]; }
    a0c = a0n1;
    a0n1 = a0n2;
  }

  // Accumulate into one of NT partial tiles.
  // C/D layout (verified m74/m101): col=lane&31, row=(r&3)+8*(r>>2)+4*(lane>>5)
  float* tp = tiles + (size_t)(blk & (NT - 1)) * 1024;
#pragma unroll
  for (int r = 0; r < 16; ++r) {
    const int brow = (r & 3) + 8 * (r >> 2) + 4 * g;
    atomicAdd(tp + brow * 32 + bo, acc[r]);
  }
}

// Final reduce: out[idx] = sum over NT tiles.
__global__ __launch_bounds__(256) void k_red(const float* __restrict__ tiles,
                                             float* __restrict__ out) {
  const int idx = blockIdx.x * 256 + (int)threadIdx.x;
  float s = 0.f;
  for (int t = 0; t < NT; ++t) s += tiles[(size_t)t * 1024 + idx];
  out[idx] = s;
}

extern "C" void kernel_launch(void* const* d_in, const int* in_sizes, int n_in,
                              void* d_out, int out_size, void* d_ws, size_t ws_size,
                              hipStream_t stream) {
  const float* nh = (const float*)d_in[0];  // [32,4,32]
  const float* T  = (const float*)d_in[1];  // [33,33,33,33,32]
  float* out = (float*)d_out;               // [32,32] fp32
  char* ws = (char*)d_ws;
  float* a0T   = (float*)(ws + OFF_A0T);
  float* D     = (float*)(ws + OFF_D);
  float* tiles = (float*)(ws + OFF_TILES);

  k_pre<<<dim3(141, 32), 256, 0, stream>>>(nh, a0T, D, tiles);
  k_main<<<NBLK, 64, 0, stream>>>(T, a0T, D, tiles);
  k_red<<<4, 256, 0, stream>>>(tiles, out);
}